// Round 1
// baseline (284.183 us; speedup 1.0000x reference)
//
#include <hip/hip_runtime.h>
#include <hip/hip_fp16.h>

#define OUTN 16384
#define BATCH 2048
#define DIM   256

typedef _Float16 half8 __attribute__((ext_vector_type(8)));
typedef float    floatx4 __attribute__((ext_vector_type(4)));

// ---------------- P0a: convert x to f16 + row norms ----------------
__global__ void prep_x(const float* __restrict__ x, _Float16* __restrict__ xh,
                       float* __restrict__ rown) {
    int b = blockIdx.x, t = threadIdx.x;           // 2048 blocks x 256 thr
    float v = x[b * DIM + t];
    xh[b * DIM + t] = (_Float16)v;
    float s = v * v;
    for (int off = 32; off; off >>= 1) s += __shfl_down(s, off, 64);
    __shared__ float wsum[4];
    if ((t & 63) == 0) wsum[t >> 6] = s;
    __syncthreads();
    if (t == 0) rown[b] = wsum[0] + wsum[1] + wsum[2] + wsum[3];
}

// ---------------- P0b: transpose kernel -> kT[j][d] as f16 ----------------
__global__ void prep_kT(const float* __restrict__ kern, _Float16* __restrict__ kT) {
    __shared__ float tile[32][33];
    int j0 = blockIdx.x * 32, d0 = blockIdx.y * 32;
    int tx = threadIdx.x, ty = threadIdx.y;        // (32,8)
    for (int r = ty; r < 32; r += 8)
        tile[r][tx] = kern[(size_t)(d0 + r) * OUTN + j0 + tx];
    __syncthreads();
    for (int r = ty; r < 32; r += 8)
        kT[(size_t)(j0 + r) * DIM + d0 + tx] = (_Float16)tile[tx][r];
}

// ---------------- P0c: exact fp32 column norms ----------------
__global__ void prep_coln(const float* __restrict__ kern, float* __restrict__ coln) {
    int j = blockIdx.x * 256 + threadIdx.x;        // 64 blocks
    float s = 0.f;
    for (int d = 0; d < DIM; d++) {
        float v = kern[(size_t)d * OUTN + j];
        s = fmaf(v, v, s);
    }
    coln[j] = s;
}

// ---------------- P1: f16 MFMA GEMM -> approx norms2 into d_out ----------------
// 128x128 tile, BK=64, 4 waves (2x2), each wave 4x4 tiles of 16x16x32.
__global__ __launch_bounds__(256) void gemm_norms(
        const _Float16* __restrict__ xh, const _Float16* __restrict__ kT,
        const float* __restrict__ rown, const float* __restrict__ coln,
        float* __restrict__ out) {
    __shared__ __align__(16) _Float16 As[128 * 64];
    __shared__ __align__(16) _Float16 Bs[128 * 64];
    int tid  = threadIdx.x;
    int col0 = blockIdx.x * 128;   // units (N)
    int row0 = blockIdx.y * 128;   // batch (M)
    int wid = tid >> 6, lane = tid & 63;
    int wr = wid >> 1, wc = wid & 1;

    floatx4 acc[4][4];
    for (int i = 0; i < 4; i++)
        for (int j = 0; j < 4; j++)
            acc[i][j] = (floatx4){0.f, 0.f, 0.f, 0.f};

    for (int kt = 0; kt < 4; kt++) {
        int k0 = kt * 64;
        // stage 128x64 A and B tiles (16B per thread per chunk)
        for (int it = 0; it < 4; it++) {
            int chunk = it * 256 + tid;
            int r = chunk >> 3, s8 = (chunk & 7) * 8;
            *(float4*)(&As[r * 64 + s8]) =
                *(const float4*)(&xh[(size_t)(row0 + r) * DIM + k0 + s8]);
            *(float4*)(&Bs[r * 64 + s8]) =
                *(const float4*)(&kT[(size_t)(col0 + r) * DIM + k0 + s8]);
        }
        __syncthreads();
        for (int s = 0; s < 2; s++) {
            int kk = s * 32 + (lane >> 4) * 8;
            half8 af[4], bf[4];
            for (int i = 0; i < 4; i++)
                af[i] = *(half8*)(&As[(wr * 64 + i * 16 + (lane & 15)) * 64 + kk]);
            for (int j = 0; j < 4; j++)
                bf[j] = *(half8*)(&Bs[(wc * 64 + j * 16 + (lane & 15)) * 64 + kk]);
            for (int i = 0; i < 4; i++)
                for (int j = 0; j < 4; j++)
                    acc[i][j] = __builtin_amdgcn_mfma_f32_16x16x32_f16(
                        af[i], bf[j], acc[i][j], 0, 0, 0);
        }
        __syncthreads();
    }
    // epilogue: norms2 = rown + coln - 2*dot  (C layout: col=lane&15, row=(lane>>4)*4+r)
    for (int i = 0; i < 4; i++) {
        for (int r = 0; r < 4; r++) {
            int orow = row0 + wr * 64 + i * 16 + (lane >> 4) * 4 + r;
            float rn = rown[orow];
            for (int j = 0; j < 4; j++) {
                int ocol = col0 + wc * 64 + j * 16 + (lane & 15);
                out[(size_t)orow * OUTN + ocol] = rn + coln[ocol] - 2.0f * acc[i][j][r];
            }
        }
    }
}

// ---------------- P2: per-row min + exact refinement -> wta ----------------
__global__ void refine(const float* __restrict__ outv, const float* __restrict__ x,
                       const float* __restrict__ kern, const float* __restrict__ coln,
                       int* __restrict__ wta) {
    int b = blockIdx.x, tid = threadIdx.x;         // 2048 blocks x 256 thr
    __shared__ float xrow[DIM];
    __shared__ float fred[256];
    __shared__ unsigned long long red[256];
    xrow[tid] = x[b * DIM + tid];
    const float* rowp = outv + (size_t)b * OUTN;

    // pass 1: row min of approx norms2
    float lmin = 3.4e38f;
    for (int it = 0; it < 16; it++) {
        float4 v = ((const float4*)rowp)[it * 256 + tid];
        lmin = fminf(lmin, fminf(fminf(v.x, v.y), fminf(v.z, v.w)));
    }
    fred[tid] = lmin;
    __syncthreads();
    for (int off = 128; off; off >>= 1) {
        if (tid < off) fred[tid] = fminf(fred[tid], fred[tid + off]);
        __syncthreads();
    }
    float thr = fred[0] + 0.25f;   // covers 2x max f16-GEMM error (~0.012) with margin

    // pass 2: exact fp32 recompute of candidates; key = coln[j] - 2*dot (row-const dropped)
    unsigned long long best = ~0ull;
    for (int it = 0; it < 64; it++) {
        int j = it * 256 + tid;
        float v = rowp[j];
        if (v <= thr) {
            float dot = 0.f;
            for (int d = 0; d < DIM; d++)
                dot = fmaf(xrow[d], kern[(size_t)d * OUTN + j], dot);
            float s = coln[j] - 2.f * dot;
            unsigned int key = __float_as_uint(s);
            key = (key & 0x80000000u) ? ~key : (key | 0x80000000u);
            unsigned long long p = ((unsigned long long)key << 32) | (unsigned int)j;
            best = (p < best) ? p : best;
        }
    }
    red[tid] = best;
    __syncthreads();
    for (int off = 128; off; off >>= 1) {
        if (tid < off) { if (red[tid + off] < red[tid]) red[tid] = red[tid + off]; }
        __syncthreads();
    }
    if (tid == 0) wta[b] = (int)(red[0] & 0xFFFFFFFFu);
}

// ---------------- P3: out *= gaussian neighbourhood ----------------
__global__ void finalize(float* __restrict__ out, const int* __restrict__ wta) {
    size_t gid  = (size_t)blockIdx.x * 256 + threadIdx.x;   // float4 index
    size_t base = gid * 4;
    int b  = (int)(base >> 14);
    int j0 = (int)(base & 16383);
    int w  = wta[b];
    int wrr = w >> 7, wcc = w & 127;
    int r  = j0 >> 7;                 // j0 % 4 == 0 -> all 4 elements same grid row
    int dr = r - wrr;
    int drsq = dr * dr;
    int c0 = j0 & 127;
    float4 res;
    float* rp = out + base;
    {
        int dc = c0 - wcc;     int d2 = drsq + dc * dc;
        res.x = (d2 <= 720) ? __expf(-0.125f * (float)d2) * fmaxf(rp[0], 0.f) : 0.f;
    }
    {
        int dc = c0 + 1 - wcc; int d2 = drsq + dc * dc;
        res.y = (d2 <= 720) ? __expf(-0.125f * (float)d2) * fmaxf(rp[1], 0.f) : 0.f;
    }
    {
        int dc = c0 + 2 - wcc; int d2 = drsq + dc * dc;
        res.z = (d2 <= 720) ? __expf(-0.125f * (float)d2) * fmaxf(rp[2], 0.f) : 0.f;
    }
    {
        int dc = c0 + 3 - wcc; int d2 = drsq + dc * dc;
        res.w = (d2 <= 720) ? __expf(-0.125f * (float)d2) * fmaxf(rp[3], 0.f) : 0.f;
    }
    ((float4*)out)[gid] = res;
}

extern "C" void kernel_launch(void* const* d_in, const int* in_sizes, int n_in,
                              void* d_out, int out_size, void* d_ws, size_t ws_size,
                              hipStream_t stream) {
    const float* x    = (const float*)d_in[0];   // (2048, 256) fp32
    const float* kern = (const float*)d_in[1];   // (256, 16384) fp32
    float* out = (float*)d_out;                  // (2048, 16384) fp32
    char* ws = (char*)d_ws;

    // ws layout (9.3 MB): xh 1MB | kT 8MB | coln 64KB | rown 8KB | wta 8KB
    _Float16* xh  = (_Float16*)(ws);
    _Float16* kT  = (_Float16*)(ws + 1048576);
    float* coln   = (float*)(ws + 9437184);
    float* rown   = (float*)(ws + 9502720);
    int*   wta    = (int*)(ws + 9510912);

    prep_x<<<BATCH, DIM, 0, stream>>>(x, xh, rown);
    prep_kT<<<dim3(OUTN / 32, DIM / 32), dim3(32, 8), 0, stream>>>(kern, kT);
    prep_coln<<<OUTN / 256, 256, 0, stream>>>(kern, coln);
    gemm_norms<<<dim3(OUTN / 128, BATCH / 128), 256, 0, stream>>>(xh, kT, rown, coln, out);
    refine<<<BATCH, 256, 0, stream>>>(out, x, kern, coln, wta);
    finalize<<<(BATCH * OUTN / 4) / 256, 256, 0, stream>>>(out, wta);
}

// Round 2
// 206.246 us; speedup vs baseline: 1.3779x; 1.3779x over previous
//
#include <hip/hip_runtime.h>
#include <hip/hip_fp16.h>

#define OUTN 16384
#define BATCH 2048
#define DIM   256
#define NCB   (OUTN / 128)     // 128 column-blocks per row

typedef _Float16 half8 __attribute__((ext_vector_type(8)));
typedef float    floatx4 __attribute__((ext_vector_type(4)));
typedef unsigned long long u64;

__device__ __forceinline__ void gl2lds16(const void* g, void* l) {
    __builtin_amdgcn_global_load_lds(
        (const __attribute__((address_space(1))) void*)g,
        (__attribute__((address_space(3))) void*)l, 16, 0, 0);
}

// monotone float->uint map packed with column index (low 32): min(pack) = argmin
__device__ __forceinline__ u64 packkey(float v, int col) {
    unsigned u = __float_as_uint(v);
    u = (u & 0x80000000u) ? ~u : (u | 0x80000000u);
    return ((u64)u << 32) | (unsigned)col;
}
__device__ __forceinline__ float unpackval(u64 p) {
    unsigned u = (unsigned)(p >> 32);
    u = (u & 0x80000000u) ? (u & 0x7fffffffu) : ~u;
    return __uint_as_float(u);
}

// ---------------- P0a: x -> f16 + row norms ----------------
__global__ void prep_x(const float* __restrict__ x, _Float16* __restrict__ xh,
                       float* __restrict__ rown) {
    int b = blockIdx.x, t = threadIdx.x;           // 2048 x 256
    float v = x[b * DIM + t];
    xh[b * DIM + t] = (_Float16)v;
    float s = v * v;
    for (int off = 32; off; off >>= 1) s += __shfl_down(s, off, 64);
    __shared__ float wsum[4];
    if ((t & 63) == 0) wsum[t >> 6] = s;
    __syncthreads();
    if (t == 0) rown[b] = wsum[0] + wsum[1] + wsum[2] + wsum[3];
}

// ---------------- P0b: transpose kernel -> kT[j][d] f16, fused fp32 col norms ----------------
__global__ __launch_bounds__(256) void prep_kTn(const float* __restrict__ kern,
                                                _Float16* __restrict__ kT,
                                                float* __restrict__ coln) {
    __shared__ float tile[64][65];
    __shared__ float npart[4][64];
    int t = threadIdx.x, tx = t & 63, ty = t >> 6;
    int j0 = blockIdx.x * 64;                      // 256 blocks
    float nrm = 0.f;
    for (int dc = 0; dc < DIM; dc += 64) {
        __syncthreads();
        for (int it = 0; it < 16; it++) {
            int d = dc + ty + it * 4;
            float v = kern[(size_t)d * OUTN + j0 + tx];
            tile[ty + it * 4][tx] = v;
            nrm = fmaf(v, v, nrm);
        }
        __syncthreads();
        for (int c = t; c < 512; c += 256) {       // 64j x 64d f16 out, 16B chunks
            int j = c >> 3, o8 = (c & 7) * 8;
            half8 h;
            for (int u = 0; u < 8; u++) h[u] = (_Float16)tile[o8 + u][j];
            *(half8*)&kT[(size_t)(j0 + j) * DIM + dc + o8] = h;
        }
    }
    npart[ty][tx] = nrm;
    __syncthreads();
    if (t < 64) coln[j0 + t] = npart[0][t] + npart[1][t] + npart[2][t] + npart[3][t];
}

// ---------------- P1: f16 MFMA GEMM -> norms2 into d_out + per-(row,128col) top-2 candidates ----
__global__ __launch_bounds__(256) void gemm_norms(
        const _Float16* __restrict__ xh, const _Float16* __restrict__ kT,
        const float* __restrict__ rown, const float* __restrict__ coln,
        float* __restrict__ out, u64* __restrict__ blockcand) {
    __shared__ __align__(16) char smem[32768];
    _Float16* As = (_Float16*)smem;                // 128 x 64
    _Float16* Bs = (_Float16*)(smem + 16384);      // 128 x 64
    u64* cand = (u64*)smem;                        // 128 x 32, reused after k-loop
    int tid  = threadIdx.x;
    int col0 = blockIdx.x * 128;
    int row0 = blockIdx.y * 128;
    int wid = tid >> 6, lane = tid & 63;
    int wr = wid >> 1, wc = wid & 1;
    int l15 = lane & 15, l4 = lane >> 4;

    floatx4 acc[4][4];
    for (int i = 0; i < 4; i++)
        for (int j = 0; j < 4; j++)
            acc[i][j] = (floatx4){0.f, 0.f, 0.f, 0.f};

    for (int kt = 0; kt < 4; kt++) {
        int k0 = kt * 64;
        for (int it = 0; it < 4; it++) {
            int chunk = it * 256 + tid;            // 1024 chunks x 16B
            int r = chunk >> 3, k8 = (chunk & 7) * 8;
            gl2lds16(&xh[(size_t)(row0 + r) * DIM + k0 + k8], &As[chunk * 8]);
            gl2lds16(&kT[(size_t)(col0 + r) * DIM + k0 + k8], &Bs[chunk * 8]);
        }
        __syncthreads();
        for (int s = 0; s < 2; s++) {
            int kk = s * 32 + l4 * 8;
            half8 af[4], bf[4];
            for (int i = 0; i < 4; i++)
                af[i] = *(half8*)&As[(wr * 64 + i * 16 + l15) * 64 + kk];
            for (int j = 0; j < 4; j++)
                bf[j] = *(half8*)&Bs[(wc * 64 + j * 16 + l15) * 64 + kk];
            for (int i = 0; i < 4; i++)
                for (int j = 0; j < 4; j++)
                    acc[i][j] = __builtin_amdgcn_mfma_f32_16x16x32_f16(
                        af[i], bf[j], acc[i][j], 0, 0, 0);
        }
        __syncthreads();
    }

    // epilogue: norms2 = rown + coln - 2*dot; write + per-thread per-row min of its 4 cols
    float cn[4]; int oc[4];
    for (int j = 0; j < 4; j++) {
        oc[j] = col0 + wc * 64 + j * 16 + l15;
        cn[j] = coln[oc[j]];
    }
    for (int i = 0; i < 4; i++) {
        for (int r = 0; r < 4; r++) {
            int row_l = wr * 64 + i * 16 + l4 * 4 + r;
            int orow  = row0 + row_l;
            float rn = rown[orow];
            u64 best = ~0ull;
            for (int j = 0; j < 4; j++) {
                float val = rn + cn[j] - 2.0f * acc[i][j][r];
                out[(size_t)orow * OUTN + oc[j]] = val;
                u64 p = packkey(val, oc[j]);
                if (p < best) best = p;
            }
            cand[row_l * 32 + wc * 16 + l15] = best;
        }
    }
    __syncthreads();
    if (tid < 128) {                               // per row: top-2 of 32 thread-mins
        u64 m1 = ~0ull, m2 = ~0ull;
        for (int s = 0; s < 32; s++) {
            u64 v = cand[tid * 32 + s];
            if (v < m1) { m2 = m1; m1 = v; }
            else if (v < m2) { m2 = v; }
        }
        size_t base = (size_t)(row0 + tid) * (NCB * 2) + blockIdx.x * 2;
        blockcand[base]     = m1;
        blockcand[base + 1] = m2;
    }
}

// ---------------- P2: candidate-only argmin refinement + fused gaussian finalize ----------------
__global__ __launch_bounds__(256) void refine_finalize(
        const u64* __restrict__ blockcand, const float* __restrict__ x,
        const float* __restrict__ kern, const float* __restrict__ coln,
        float* __restrict__ out) {
    int b = blockIdx.x, t = threadIdx.x;           // 2048 x 256
    __shared__ float xrow[DIM];
    __shared__ u64 red[256];
    xrow[t] = x[b * DIM + t];
    u64 e = blockcand[(size_t)b * 256 + t];
    red[t] = e;
    __syncthreads();
    for (int off = 128; off; off >>= 1) {
        if (t < off) { u64 o = red[t + off]; if (o < red[t]) red[t] = o; }
        __syncthreads();
    }
    float minv = unpackval(red[0]);
    __syncthreads();

    // exact fp32 recompute of candidates within delta of approx min
    float ve = unpackval(e);
    u64 p = ~0ull;
    if (ve <= minv + 0.125f) {
        int j = (int)(e & 0xffffffffu);
        float dot = 0.f;
        for (int d = 0; d < DIM; d++)
            dot = fmaf(xrow[d], kern[(size_t)d * OUTN + j], dot);
        p = packkey(coln[j] - 2.0f * dot, j);      // row-constant ||x||^2 dropped
    }
    red[t] = p;
    __syncthreads();
    for (int off = 128; off; off >>= 1) {
        if (t < off) { u64 o = red[t + off]; if (o < red[t]) red[t] = o; }
        __syncthreads();
    }
    int w = (int)(red[0] & 0xffffffffu);
    int wrr = w >> 7, wcc = w & 127;

    // fused finalize: out = exp(-0.125*d2) * max(norms2,0), 0 outside the disk
    float* rowp = out + (size_t)b * OUTN;
    for (int it = 0; it < 16; it++) {
        int idx4 = it * 256 + t;
        int j0 = idx4 * 4;
        int r  = j0 >> 7, c0 = j0 & 127;
        int dr = r - wrr, drsq = dr * dr;
        float4 res;
        {
            int dc = c0 - wcc;     int d2 = drsq + dc * dc;
            res.x = (d2 <= 720) ? __expf(-0.125f * (float)d2) * fmaxf(rowp[j0], 0.f) : 0.f;
        }
        {
            int dc = c0 + 1 - wcc; int d2 = drsq + dc * dc;
            res.y = (d2 <= 720) ? __expf(-0.125f * (float)d2) * fmaxf(rowp[j0 + 1], 0.f) : 0.f;
        }
        {
            int dc = c0 + 2 - wcc; int d2 = drsq + dc * dc;
            res.z = (d2 <= 720) ? __expf(-0.125f * (float)d2) * fmaxf(rowp[j0 + 2], 0.f) : 0.f;
        }
        {
            int dc = c0 + 3 - wcc; int d2 = drsq + dc * dc;
            res.w = (d2 <= 720) ? __expf(-0.125f * (float)d2) * fmaxf(rowp[j0 + 3], 0.f) : 0.f;
        }
        ((float4*)rowp)[idx4] = res;
    }
}

extern "C" void kernel_launch(void* const* d_in, const int* in_sizes, int n_in,
                              void* d_out, int out_size, void* d_ws, size_t ws_size,
                              hipStream_t stream) {
    const float* x    = (const float*)d_in[0];   // (2048, 256) fp32
    const float* kern = (const float*)d_in[1];   // (256, 16384) fp32
    float* out = (float*)d_out;                  // (2048, 16384) fp32
    char* ws = (char*)d_ws;

    // ws: xh 1MB | kT 8MB | coln 64KB | rown 8KB | blockcand 4MB  (~14 MB)
    _Float16* xh   = (_Float16*)(ws);
    _Float16* kT   = (_Float16*)(ws + (1u << 20));
    float*    coln = (float*)(ws + (9u << 20));
    float*    rown = (float*)(ws + (9u << 20) + 65536);
    u64* blockcand = (u64*)(ws + (10u << 20));

    prep_x<<<BATCH, DIM, 0, stream>>>(x, xh, rown);
    prep_kTn<<<OUTN / 64, 256, 0, stream>>>(kern, kT, coln);
    gemm_norms<<<dim3(OUTN / 128, BATCH / 128), 256, 0, stream>>>(xh, kT, rown, coln, out, blockcand);
    refine_finalize<<<BATCH, 256, 0, stream>>>(blockcand, x, kern, coln, out);
}

// Round 3
// 202.056 us; speedup vs baseline: 1.4065x; 1.0207x over previous
//
#include <hip/hip_runtime.h>
#include <hip/hip_fp16.h>

#define OUTN 16384
#define BATCH 2048
#define DIM   256

typedef _Float16 half8 __attribute__((ext_vector_type(8)));
typedef float    floatx4 __attribute__((ext_vector_type(4)));
typedef unsigned long long u64;

__device__ __forceinline__ void gl2lds16(const void* g, void* l) {
    __builtin_amdgcn_global_load_lds(
        (const __attribute__((address_space(1))) void*)g,
        (__attribute__((address_space(3))) void*)l, 16, 0, 0);
}

// monotone float->uint map packed with column index (low 32): min(pack) = argmin
__device__ __forceinline__ u64 packkey(float v, int col) {
    unsigned u = __float_as_uint(v);
    u = (u & 0x80000000u) ? ~u : (u | 0x80000000u);
    return ((u64)u << 32) | (unsigned)col;
}
__device__ __forceinline__ float unpackval(u64 p) {
    unsigned u = (unsigned)(p >> 32);
    u = (u & 0x80000000u) ? (u & 0x7fffffffu) : ~u;
    return __uint_as_float(u);
}

// ---------------- P0 fused: [0,512) kT-transpose+colnorm halves; [512,2560) x->f16+rownorm ----
__global__ __launch_bounds__(256) void prep_all(
        const float* __restrict__ x, const float* __restrict__ kern,
        _Float16* __restrict__ xh, float* __restrict__ rown,
        _Float16* __restrict__ kT, float* __restrict__ colnp) {
    int blk = blockIdx.x, t = threadIdx.x;
    if (blk < 512) {
        __shared__ float tile[64][65];
        __shared__ float npart[4][64];
        int tx = t & 63, ty = t >> 6;
        int j0 = (blk >> 1) * 64;
        int dhalf = blk & 1, dbase = dhalf * 128;
        float nrm = 0.f;
        for (int pc = 0; pc < 2; pc++) {
            int dc = dbase + pc * 64;
            __syncthreads();
            for (int it = 0; it < 16; it++) {
                int d = dc + ty + it * 4;
                float v = kern[(size_t)d * OUTN + j0 + tx];
                tile[ty + it * 4][tx] = v;
                nrm = fmaf(v, v, nrm);
            }
            __syncthreads();
            for (int c = t; c < 512; c += 256) {   // 64j x 64d f16 out, 16B chunks
                int j = c >> 3, o8 = (c & 7) * 8;
                half8 h;
                for (int u = 0; u < 8; u++) h[u] = (_Float16)tile[o8 + u][j];
                *(half8*)&kT[(size_t)(j0 + j) * DIM + dc + o8] = h;
            }
        }
        npart[ty][tx] = nrm;
        __syncthreads();
        if (t < 64)
            colnp[(size_t)dhalf * OUTN + j0 + t] =
                npart[0][t] + npart[1][t] + npart[2][t] + npart[3][t];
    } else {
        int b = blk - 512;                         // 2048 rows
        float v = x[b * DIM + t];
        xh[b * DIM + t] = (_Float16)v;
        float s = v * v;
        for (int off = 32; off; off >>= 1) s += __shfl_down(s, off, 64);
        __shared__ float wsum[4];
        if ((t & 63) == 0) wsum[t >> 6] = s;
        __syncthreads();
        if (t == 0) rown[b] = wsum[0] + wsum[1] + wsum[2] + wsum[3];
    }
}

// ---------------- P1: f16 MFMA GEMM (XOR-swizzled LDS) -> norms2 + top-2/128-col candidates ----
template <bool NF16>
__global__ __launch_bounds__(256) void gemm_norms(
        const _Float16* __restrict__ xh, const _Float16* __restrict__ kT,
        const float* __restrict__ rown, const float* __restrict__ colnp,
        void* __restrict__ n2out, u64* __restrict__ blockcand) {
    __shared__ __align__(16) char smem[32768];
    _Float16* As = (_Float16*)smem;                // 128 rows x 64 (16B-granules XOR-swizzled)
    _Float16* Bs = (_Float16*)(smem + 16384);
    u64* cand = (u64*)smem;                        // 128 x 32, reused after k-loop
    int tid  = threadIdx.x;
    int col0 = blockIdx.x * 128;
    int row0 = blockIdx.y * 128;
    int wid = tid >> 6, lane = tid & 63;
    int wr = wid >> 1, wc = wid & 1;
    int l15 = lane & 15, l4 = lane >> 4;
    int xh7 = l15 & 7;                             // XOR key for frag reads

    floatx4 acc[4][4];
    for (int i = 0; i < 4; i++)
        for (int j = 0; j < 4; j++)
            acc[i][j] = (floatx4){0.f, 0.f, 0.f, 0.f};

    for (int kt = 0; kt < 4; kt++) {
        int k0 = kt * 64;
        for (int it = 0; it < 4; it++) {
            int chunk = it * 256 + tid;            // 1024 chunks x 16B
            int r = chunk >> 3, gg = chunk & 7;
            int ksw = (gg ^ (r & 7)) * 8;          // swizzled source granule
            gl2lds16(&xh[(size_t)(row0 + r) * DIM + k0 + ksw], &As[chunk * 8]);
            gl2lds16(&kT[(size_t)(col0 + r) * DIM + k0 + ksw], &Bs[chunk * 8]);
        }
        __syncthreads();
        for (int s = 0; s < 2; s++) {
            int g = s * 4 + l4;                    // logical 16B-granule within row
            int sw = (g ^ xh7) * 8;                // physical element offset
            half8 af[4], bf[4];
            for (int i = 0; i < 4; i++)
                af[i] = *(half8*)&As[(wr * 64 + i * 16 + l15) * 64 + sw];
            for (int j = 0; j < 4; j++)
                bf[j] = *(half8*)&Bs[(wc * 64 + j * 16 + l15) * 64 + sw];
            for (int i = 0; i < 4; i++)
                for (int j = 0; j < 4; j++)
                    acc[i][j] = __builtin_amdgcn_mfma_f32_16x16x32_f16(
                        af[i], bf[j], acc[i][j], 0, 0, 0);
        }
        __syncthreads();
    }

    // epilogue: norms2 = rown + coln - 2*dot; store + per-thread per-row min of its 4 cols
    float cn[4]; int oc[4];
    for (int j = 0; j < 4; j++) {
        oc[j] = col0 + wc * 64 + j * 16 + l15;
        cn[j] = colnp[oc[j]] + colnp[OUTN + oc[j]];
    }
    for (int i = 0; i < 4; i++) {
        for (int r = 0; r < 4; r++) {
            int row_l = wr * 64 + i * 16 + l4 * 4 + r;
            int orow  = row0 + row_l;
            float rn = rown[orow];
            u64 best = ~0ull;
            for (int j = 0; j < 4; j++) {
                float val = rn + cn[j] - 2.0f * acc[i][j][r];
                size_t oi = (size_t)orow * OUTN + oc[j];
                if (NF16) ((_Float16*)n2out)[oi] = (_Float16)val;
                else      ((float*)n2out)[oi]    = val;
                u64 p = packkey(val, oc[j]);
                if (p < best) best = p;
            }
            cand[row_l * 32 + wc * 16 + l15] = best;
        }
    }
    __syncthreads();
    if (tid < 128) {                               // per row: top-2 of 32 thread-mins
        u64 m1 = ~0ull, m2 = ~0ull;
        for (int s = 0; s < 32; s++) {
            u64 v = cand[tid * 32 + s];
            if (v < m1) { m2 = m1; m1 = v; }
            else if (v < m2) { m2 = v; }
        }
        size_t base = (size_t)(row0 + tid) * 256 + blockIdx.x * 2;
        blockcand[base]     = m1;
        blockcand[base + 1] = m2;
    }
}

// ---------------- P2: candidate argmin refinement + fused gaussian finalize ----------------
template <bool NF16>
__global__ __launch_bounds__(256) void refine_finalize(
        const u64* __restrict__ blockcand, const float* __restrict__ x,
        const float* __restrict__ kern, const float* __restrict__ colnp,
        const void* __restrict__ n2in, float* __restrict__ out) {
    int b = blockIdx.x, t = threadIdx.x;           // 2048 x 256
    __shared__ float xrow[DIM];
    __shared__ u64 red[256];
    xrow[t] = x[b * DIM + t];
    u64 e = blockcand[(size_t)b * 256 + t];
    red[t] = e;
    __syncthreads();
    for (int off = 128; off; off >>= 1) {
        if (t < off) { u64 o = red[t + off]; if (o < red[t]) red[t] = o; }
        __syncthreads();
    }
    float minv = unpackval(red[0]);
    __syncthreads();

    // exact fp32 recompute of candidates within delta of approx min
    float ve = unpackval(e);
    u64 p = ~0ull;
    if (ve <= minv + 0.125f) {
        int j = (int)(e & 0xffffffffu);
        float dot = 0.f;
        for (int d = 0; d < DIM; d++)
            dot = fmaf(xrow[d], kern[(size_t)d * OUTN + j], dot);
        p = packkey((colnp[j] + colnp[OUTN + j]) - 2.0f * dot, j);  // row-const dropped
    }
    red[t] = p;
    __syncthreads();
    for (int off = 128; off; off >>= 1) {
        if (t < off) { u64 o = red[t + off]; if (o < red[t]) red[t] = o; }
        __syncthreads();
    }
    int w = (int)(red[0] & 0xffffffffu);
    int wrr = w >> 7, wcc = w & 127;

    const _Float16* r16 = (const _Float16*)n2in + (size_t)b * OUTN;
    const float*    r32 = (const float*)n2in    + (size_t)b * OUTN;
    float* rowp = out + (size_t)b * OUTN;
    for (int it = 0; it < 16; it++) {
        int idx4 = it * 256 + t;
        int j0 = idx4 * 4;
        int r  = j0 >> 7, c0 = j0 & 127;
        int dr = r - wrr, drsq = dr * dr;
        float4 res;
        {
            int dc = c0 - wcc;     int d2 = drsq + dc * dc;
            float v = (d2 <= 720) ? (NF16 ? (float)r16[j0]     : r32[j0])     : 0.f;
            res.x = (d2 <= 720) ? __expf(-0.125f * (float)d2) * fmaxf(v, 0.f) : 0.f;
        }
        {
            int dc = c0 + 1 - wcc; int d2 = drsq + dc * dc;
            float v = (d2 <= 720) ? (NF16 ? (float)r16[j0 + 1] : r32[j0 + 1]) : 0.f;
            res.y = (d2 <= 720) ? __expf(-0.125f * (float)d2) * fmaxf(v, 0.f) : 0.f;
        }
        {
            int dc = c0 + 2 - wcc; int d2 = drsq + dc * dc;
            float v = (d2 <= 720) ? (NF16 ? (float)r16[j0 + 2] : r32[j0 + 2]) : 0.f;
            res.z = (d2 <= 720) ? __expf(-0.125f * (float)d2) * fmaxf(v, 0.f) : 0.f;
        }
        {
            int dc = c0 + 3 - wcc; int d2 = drsq + dc * dc;
            float v = (d2 <= 720) ? (NF16 ? (float)r16[j0 + 3] : r32[j0 + 3]) : 0.f;
            res.w = (d2 <= 720) ? __expf(-0.125f * (float)d2) * fmaxf(v, 0.f) : 0.f;
        }
        ((float4*)rowp)[idx4] = res;
    }
}

extern "C" void kernel_launch(void* const* d_in, const int* in_sizes, int n_in,
                              void* d_out, int out_size, void* d_ws, size_t ws_size,
                              hipStream_t stream) {
    const float* x    = (const float*)d_in[0];   // (2048, 256) fp32
    const float* kern = (const float*)d_in[1];   // (256, 16384) fp32
    float* out = (float*)d_out;                  // (2048, 16384) fp32
    char* ws = (char*)d_ws;

    // ws: xh 1MB | kT 8MB | colnp 128KB | rown 8KB | blockcand 4MB | [n2h 64MB if room]
    _Float16* xh   = (_Float16*)(ws);
    _Float16* kT   = (_Float16*)(ws + (1u << 20));
    float*   colnp = (float*)(ws + (9u << 20));
    float*   rown  = (float*)(ws + (9u << 20) + (128u << 10));
    u64* blockcand = (u64*)(ws + (10u << 20));
    void*    n2h   = (void*)(ws + (14u << 20));
    bool f16path = ws_size >= ((size_t)78 << 20);

    prep_all<<<2560, 256, 0, stream>>>(x, kern, xh, rown, kT, colnp);
    if (f16path) {
        gemm_norms<true><<<dim3(OUTN / 128, BATCH / 128), 256, 0, stream>>>(
            xh, kT, rown, colnp, n2h, blockcand);
        refine_finalize<true><<<BATCH, 256, 0, stream>>>(
            blockcand, x, kern, colnp, n2h, out);
    } else {
        gemm_norms<false><<<dim3(OUTN / 128, BATCH / 128), 256, 0, stream>>>(
            xh, kT, rown, colnp, (void*)out, blockcand);
        refine_finalize<false><<<BATCH, 256, 0, stream>>>(
            blockcand, x, kern, colnp, (const void*)out, out);
    }
}